// Round 13
// baseline (109.718 us; speedup 1.0000x reference)
//
#include <hip/hip_runtime.h>

// Problem: B=16384, X_DIM=1024, K=64, fp32 in/out.
// out[b] = 0.5 * ( sum_k (x_b . V[:,k])^2  -  sum_i x_bi^2 w_i ),  w_i = sum_k V[i][k]^2
//
// R13: continue R12's winning lever (cut the instruction/byte stream):
//  - block = 32 rows; wave = 32 rows x 4 i-tiles: V-fragments loaded ONCE per
//    tile and reused across both 16-row strips -> frag traffic 128->64 MB,
//    frag loads per MFMA halved.
//  - x read direct from global (A-fragment pattern; staging was neutral in R6):
//    no xbuf LDS, no swizzle, no staging barrier -> K-loop is barrier-free.
//  - single-product pure-bf16 (RNE both sides), fp32 acc (absmax ~1.0 vs 3.28).
// Occupancy held at 16 waves/CU (2 blocks/CU x 8 waves, LDS ~66 KB, VGPR<=128).

typedef short short8 __attribute__((ext_vector_type(8)));   // 8 bf16 = 4 VGPRs
typedef float f32x4 __attribute__((ext_vector_type(4)));

constexpr int XD = 1024;
constexpr int KD = 64;

static __device__ __forceinline__ unsigned short f2bf(float f) {
    union { float f; unsigned u; } v; v.f = f;
    unsigned r = v.u + 0x7FFFu + ((v.u >> 16) & 1u);   // RNE
    return (unsigned short)(r >> 16);
}
static __device__ __forceinline__ unsigned fbits(float f) {
    union { float f; unsigned u; } v; v.f = f; return v.u;
}

// ---- prep: blocks 0..31 build bf16 B-fragments (RNE); 32..35 build w ----
// B-fragment layout (mfma_f32_16x16x32_bf16): lane l holds B[k=(l>>4)*8+j][n=l&15]
// ws: bh @ 0 (131072 B) | wc @ 131072 (4096 B)
__global__ void prep_kernel(const float* __restrict__ v,
                            unsigned short* __restrict__ bh,
                            float* __restrict__ wc) {
    if (blockIdx.x < 32) {
        int idx = blockIdx.x * 256 + threadIdx.x;
        int it = idx >> 8;
        int r  = idx & 255;
        int t  = r >> 6;
        int l  = r & 63;
        int q  = l >> 4, m = l & 15;
        int base_i = it * 32 + q * 8;
        int n = t * 16 + m;
        size_t fo = ((size_t)(it * 4 + t) * 64 + l) * 8;
#pragma unroll
        for (int j = 0; j < 8; ++j) {
            float val = v[(size_t)(base_i + j) * KD + n];
            bh[fo + j] = f2bf(val);
        }
    } else {
        int i = (blockIdx.x - 32) * 256 + threadIdx.x;   // 0..1023
        const f32x4* vp = (const f32x4*)(v + (size_t)i * KD);
        f32x4 tv[16];
#pragma unroll
        for (int qq = 0; qq < 16; ++qq) tv[qq] = vp[qq];
        float s = 0.f;
#pragma unroll
        for (int qq = 0; qq < 16; ++qq) {
            s = fmaf(tv[qq].x, tv[qq].x, s); s = fmaf(tv[qq].y, tv[qq].y, s);
            s = fmaf(tv[qq].z, tv[qq].z, s); s = fmaf(tv[qq].w, tv[qq].w, s);
        }
        wc[i] = s;
    }
}

// ---- main: 512 thr / 8 waves; block = 32 rows (2 strips); wave = 4 i-tiles ----
__global__ __launch_bounds__(512, 4)
void cross_r13(const float* __restrict__ x,
               const unsigned short* __restrict__ bh,
               const float* __restrict__ wc,
               float* __restrict__ out) {
    __shared__ float wlds[XD];              //  4096 B
    __shared__ float comb[7][2][64][17];    // 60928 B  pitch 17 -> conflict-free
    __shared__ float zbs[7][2][16];         //   896 B   (total ~66 KB -> 2 blocks/CU)

    const int tid = threadIdx.x;
    const int l = tid & 63;
    const int w = tid >> 6;            // wave 0..7 = i-eighth (4 tiles)
    const int q = l >> 4, m = l & 15;
    const int row0 = blockIdx.x * 32;

    // stage w (512 thr x float2, coalesced aligned)
    *(float2*)&wlds[tid * 2] = *(const float2*)(wc + tid * 2);
    __syncthreads();

    f32x4 c[2][4];
#pragma unroll
    for (int s = 0; s < 2; ++s)
#pragma unroll
        for (int t = 0; t < 4; ++t) c[s][t] = f32x4{0.f, 0.f, 0.f, 0.f};
    float z[2] = {0.f, 0.f};

    const short8* bhp = (const short8*)bh;
    const float* xr0 = x + (size_t)(row0 + m) * XD + q * 8;         // strip 0
    const float* xr1 = x + (size_t)(row0 + 16 + m) * XD + q * 8;    // strip 1

#pragma unroll
    for (int ii = 0; ii < 4; ++ii) {
        const int it = w * 4 + ii;
        const size_t fbase = (size_t)(it * 4) * 64 + l;

        // V fragments loaded ONCE, reused by both strips
        short8 vh[4];
#pragma unroll
        for (int t = 0; t < 4; ++t) vh[t] = bhp[fbase + (size_t)t * 64];

        const float* wp = &wlds[it * 32 + q * 8];
        f32x4 wa = *(const f32x4*)wp, wb = *(const f32x4*)(wp + 4);

#pragma unroll
        for (int s = 0; s < 2; ++s) {
            const float* xp = (s ? xr1 : xr0) + it * 32;
            f32x4 xa = ((const f32x4*)xp)[0];
            f32x4 xb = ((const f32x4*)xp)[1];

            float xs[8] = {xa.x, xa.y, xa.z, xa.w, xb.x, xb.y, xb.z, xb.w};
            z[s] = fmaf(xs[0]*xs[0], wa.x, z[s]); z[s] = fmaf(xs[1]*xs[1], wa.y, z[s]);
            z[s] = fmaf(xs[2]*xs[2], wa.z, z[s]); z[s] = fmaf(xs[3]*xs[3], wa.w, z[s]);
            z[s] = fmaf(xs[4]*xs[4], wb.x, z[s]); z[s] = fmaf(xs[5]*xs[5], wb.y, z[s]);
            z[s] = fmaf(xs[6]*xs[6], wb.z, z[s]); z[s] = fmaf(xs[7]*xs[7], wb.w, z[s]);

            // RNE bf16 pack of x (pairwise via v_perm)
            unsigned ahp[4];
#pragma unroll
            for (int jp = 0; jp < 4; ++jp) {
                unsigned u0 = fbits(xs[2 * jp]);
                unsigned u1 = fbits(xs[2 * jp + 1]);
                u0 += 0x7FFFu + ((u0 >> 16) & 1u);
                u1 += 0x7FFFu + ((u1 >> 16) & 1u);
                ahp[jp] = __builtin_amdgcn_perm(u1, u0, 0x07060302u);
            }
            short8 ah;
#pragma unroll
            for (int jp = 0; jp < 4; ++jp) {
                ah[2*jp]   = (short)(ahp[jp] & 0xFFFF);
                ah[2*jp+1] = (short)(ahp[jp] >> 16);
            }

#pragma unroll
            for (int t = 0; t < 4; ++t)
                c[s][t] = __builtin_amdgcn_mfma_f32_16x16x32_bf16(ah, vh[t], c[s][t], 0, 0, 0);
        }
    }

    // z: sum over q-chunks -> full-q partial z per (strip, row m) for this i-eighth
#pragma unroll
    for (int s = 0; s < 2; ++s) {
        z[s] += __shfl_xor(z[s], 16);
        z[s] += __shfl_xor(z[s], 32);
    }

    // ---- combine the 8 waves' i-eighth partials (sum BEFORE squaring) ----
    if (w > 0) {
        const int slot = w - 1;
#pragma unroll
        for (int s = 0; s < 2; ++s)
#pragma unroll
            for (int t = 0; t < 4; ++t)
#pragma unroll
                for (int r = 0; r < 4; ++r) comb[slot][s][l][t * 4 + r] = c[s][t][r];
        if (l < 16) { zbs[slot][0][l] = z[0]; zbs[slot][1][l] = z[1]; }
    }
    __syncthreads();

    if (w == 0) {
#pragma unroll
        for (int slot = 0; slot < 7; ++slot) {
#pragma unroll
            for (int s = 0; s < 2; ++s)
#pragma unroll
                for (int t = 0; t < 4; ++t)
#pragma unroll
                    for (int r = 0; r < 4; ++r) c[s][t][r] += comb[slot][s][l][t * 4 + r];
            z[0] += zbs[slot][0][m];
            z[1] += zbs[slot][1][m];
        }

#pragma unroll
        for (int s = 0; s < 2; ++s) {
            // C layout: col = l&15, row = q*4 + reg
            float p[4] = {0.f, 0.f, 0.f, 0.f};
#pragma unroll
            for (int r = 0; r < 4; ++r)
#pragma unroll
                for (int t = 0; t < 4; ++t) p[r] = fmaf(c[s][t][r], c[s][t][r], p[r]);
#pragma unroll
            for (int mask = 1; mask < 16; mask <<= 1)
#pragma unroll
                for (int r = 0; r < 4; ++r) p[r] += __shfl_xor(p[r], mask);

            float zrow = __shfl(z[s], q * 4 + m, 16);
            if (m < 4) out[row0 + s * 16 + q * 4 + m] = 0.5f * (p[m] - zrow);
        }
    }
}

extern "C" void kernel_launch(void* const* d_in, const int* in_sizes, int n_in,
                              void* d_out, int out_size, void* d_ws, size_t ws_size,
                              hipStream_t stream) {
    const float* x = (const float*)d_in[0];      // (16384, 1024) fp32
    const float* v = (const float*)d_in[1];      // (1024, 64) fp32
    float* out = (float*)d_out;                  // (16384, 1) fp32

    unsigned short* bh = (unsigned short*)d_ws;                    // 131072 B
    float* wc = (float*)((char*)d_ws + 131072);                    //   4096 B

    const int B = in_sizes[0] / XD;              // 16384

    hipLaunchKernelGGL(prep_kernel, dim3(36), dim3(256), 0, stream, v, bh, wc);
    hipLaunchKernelGGL(cross_r13, dim3(B / 32), dim3(512), 0, stream,
                       x, bh, wc, out);
}

// Round 14
// 102.224 us; speedup vs baseline: 1.0733x; 1.0733x over previous
//
#include <hip/hip_runtime.h>

// Problem: B=16384, X_DIM=1024, K=64, fp32 in/out.
// out[b] = 0.5 * ( sum_k (x_b . V[:,k])^2  -  sum_i x_bi^2 w_i ),  w_i = sum_k V[i][k]^2
//
// R14: combine the two confirmed levers (linear-staged x: +8us when absent;
// stream-volume per row: R12's win):
//  - x staged into LDS AS BF16 (RNE at staging): A-frag = one ds_read_b128;
//    32 rows fit in 64 KB -> each V-frag load feeds 2 strips (frag traffic
//    128->64 MB) at unchanged 16 waves/CU (LDS ~70 KB, 2 blocks/CU).
//  - chunk-granularity XOR swizzle (c ^ (r&7)): stores and b128 reads at the
//    uniform 8-words/bank floor.
//  - z computed from bf16 x in-loop (unpack = shift<<16); adds ~0.2 error ->
//    absmax ~1.2 vs threshold 3.28.

typedef short short8 __attribute__((ext_vector_type(8)));   // 8 bf16 = 4 VGPRs
typedef float f32x4 __attribute__((ext_vector_type(4)));

constexpr int XD = 1024;
constexpr int KD = 64;

static __device__ __forceinline__ unsigned short f2bf(float f) {
    union { float f; unsigned u; } v; v.f = f;
    unsigned r = v.u + 0x7FFFu + ((v.u >> 16) & 1u);   // RNE
    return (unsigned short)(r >> 16);
}
static __device__ __forceinline__ unsigned fbits(float f) {
    union { float f; unsigned u; } v; v.f = f; return v.u;
}
static __device__ __forceinline__ float bitsf(unsigned u) {
    union { unsigned u; float f; } v; v.u = u; return v.f;
}
// pack two floats -> {bf16(b),bf16(a)} in one uint (RNE + v_perm)
static __device__ __forceinline__ unsigned pack2(float a, float b) {
    unsigned u0 = fbits(a), u1 = fbits(b);
    u0 += 0x7FFFu + ((u0 >> 16) & 1u);
    u1 += 0x7FFFu + ((u1 >> 16) & 1u);
    return __builtin_amdgcn_perm(u1, u0, 0x07060302u);
}

// ---- prep: blocks 0..31 build bf16 B-fragments (RNE); 32..35 build w ----
// B-fragment layout (mfma_f32_16x16x32_bf16): lane l holds B[k=(l>>4)*8+j][n=l&15]
// ws: bh @ 0 (131072 B) | wc @ 131072 (4096 B)
__global__ void prep_kernel(const float* __restrict__ v,
                            unsigned short* __restrict__ bh,
                            float* __restrict__ wc) {
    if (blockIdx.x < 32) {
        int idx = blockIdx.x * 256 + threadIdx.x;
        int it = idx >> 8;
        int r  = idx & 255;
        int t  = r >> 6;
        int l  = r & 63;
        int q  = l >> 4, m = l & 15;
        int base_i = it * 32 + q * 8;
        int n = t * 16 + m;
        size_t fo = ((size_t)(it * 4 + t) * 64 + l) * 8;
#pragma unroll
        for (int j = 0; j < 8; ++j) {
            float val = v[(size_t)(base_i + j) * KD + n];
            bh[fo + j] = f2bf(val);
        }
    } else {
        int i = (blockIdx.x - 32) * 256 + threadIdx.x;   // 0..1023
        const f32x4* vp = (const f32x4*)(v + (size_t)i * KD);
        f32x4 tv[16];
#pragma unroll
        for (int qq = 0; qq < 16; ++qq) tv[qq] = vp[qq];
        float s = 0.f;
#pragma unroll
        for (int qq = 0; qq < 16; ++qq) {
            s = fmaf(tv[qq].x, tv[qq].x, s); s = fmaf(tv[qq].y, tv[qq].y, s);
            s = fmaf(tv[qq].z, tv[qq].z, s); s = fmaf(tv[qq].w, tv[qq].w, s);
        }
        wc[i] = s;
    }
}

// ---- main: 512 thr / 8 waves; block = 32 rows (bf16 LDS); wave = 4 i-tiles ----
__global__ __launch_bounds__(512, 4)
void cross_r14(const float* __restrict__ x,
               const unsigned short* __restrict__ bh,
               const float* __restrict__ wc,
               float* __restrict__ out) {
    // xbuf: 32 rows x 1024 bf16 = 64 KB, chunk(16B)-swizzled c^(r&7).
    // After the post-loop barrier the same buffer is the combine area (61 KB).
    __shared__ __align__(16) unsigned short xbuf[32 * 1024];
    __shared__ float wlds[XD];          //  4096 B
    __shared__ float zbs[7][2][16];     //   896 B   (total ~70 KB -> 2 blocks/CU)

    const int tid = threadIdx.x;
    const int l = tid & 63;
    const int w = tid >> 6;            // wave 0..7 = i-eighth (4 tiles)
    const int q = l >> 4, m = l & 15;
    const int row0 = blockIdx.x * 32;

    // stage w (512 thr x float2, coalesced aligned)
    *(float2*)&wlds[tid * 2] = *(const float2*)(wc + tid * 2);

    // ---- stage x: 32 rows x 128 chunks (16 B bf16 each); RNE pack at staging ----
    // iteration p: idx = p*512+tid -> row r = idx>>7, chunk c = idx&127.
    // Per wave r is constant and c = c0 + lane -> swizzled store is a permutation
    // of 64 consecutive chunks = uniform 8 words/bank (b128 floor).
    f32x4 xa[8], xb[8];
#pragma unroll
    for (int p = 0; p < 8; ++p) {
        int idx = p * 512 + tid;
        int r = idx >> 7, c = idx & 127;
        const float* xp = x + (size_t)(row0 + r) * XD + c * 8;
        xa[p] = ((const f32x4*)xp)[0];
        xb[p] = ((const f32x4*)xp)[1];
    }
#pragma unroll
    for (int p = 0; p < 8; ++p) {
        int idx = p * 512 + tid;
        int r = idx >> 7, c = idx & 127;
        short8 pk;
        unsigned w0 = pack2(xa[p].x, xa[p].y);
        unsigned w1 = pack2(xa[p].z, xa[p].w);
        unsigned w2 = pack2(xb[p].x, xb[p].y);
        unsigned w3 = pack2(xb[p].z, xb[p].w);
        pk[0] = (short)(w0 & 0xFFFF); pk[1] = (short)(w0 >> 16);
        pk[2] = (short)(w1 & 0xFFFF); pk[3] = (short)(w1 >> 16);
        pk[4] = (short)(w2 & 0xFFFF); pk[5] = (short)(w2 >> 16);
        pk[6] = (short)(w3 & 0xFFFF); pk[7] = (short)(w3 >> 16);
        *(short8*)&xbuf[r * 1024 + (c ^ (r & 7)) * 8] = pk;
    }
    __syncthreads();

    // ---- compute: wave w -> i-tiles 4w..4w+3, both 16-row strips ----
    f32x4 c4[2][4];
#pragma unroll
    for (int s = 0; s < 2; ++s)
#pragma unroll
        for (int t = 0; t < 4; ++t) c4[s][t] = f32x4{0.f, 0.f, 0.f, 0.f};
    float z[2] = {0.f, 0.f};

    const short8* bhp = (const short8*)bh;

#pragma unroll
    for (int ii = 0; ii < 4; ++ii) {
        const int it = w * 4 + ii;
        const size_t fbase = (size_t)(it * 4) * 64 + l;

        // V fragments loaded ONCE, reused by both strips
        short8 vh[4];
#pragma unroll
        for (int t = 0; t < 4; ++t) vh[t] = bhp[fbase + (size_t)t * 64];

        // A fragments: chunk index cc = it*4+q of row m / m+16 ((m+16)&7 == m&7)
        const int cs = ((it * 4 + q) ^ (m & 7)) * 8;
        short8 a0 = *(const short8*)&xbuf[m * 1024 + cs];
        short8 a1 = *(const short8*)&xbuf[(m + 16) * 1024 + cs];

        const float* wp = &wlds[it * 32 + q * 8];
        f32x4 wa = *(const f32x4*)wp, wb = *(const f32x4*)(wp + 4);
        float wsv[8] = {wa.x, wa.y, wa.z, wa.w, wb.x, wb.y, wb.z, wb.w};

        // z from the bf16 values (unpack = shift<<16)
#pragma unroll
        for (int s = 0; s < 2; ++s) {
            short8 aa = s ? a1 : a0;
#pragma unroll
            for (int e = 0; e < 8; ++e) {
                float xf = bitsf(((unsigned)(unsigned short)aa[e]) << 16);
                z[s] = fmaf(xf * xf, wsv[e], z[s]);
            }
        }

#pragma unroll
        for (int t = 0; t < 4; ++t) {
            c4[0][t] = __builtin_amdgcn_mfma_f32_16x16x32_bf16(a0, vh[t], c4[0][t], 0, 0, 0);
            c4[1][t] = __builtin_amdgcn_mfma_f32_16x16x32_bf16(a1, vh[t], c4[1][t], 0, 0, 0);
        }
    }

    // z: sum over q-chunks -> full-q partial z per (strip, row m)
#pragma unroll
    for (int s = 0; s < 2; ++s) {
        z[s] += __shfl_xor(z[s], 16);
        z[s] += __shfl_xor(z[s], 32);
    }

    __syncthreads();   // all xbuf reads done; reuse as combine area
    float* comb = (float*)xbuf;   // 7 slots x 2 strips x 64 lanes x 17 = 60928 B

    if (w > 0) {
        const int slot = w - 1;
#pragma unroll
        for (int s = 0; s < 2; ++s)
#pragma unroll
            for (int t = 0; t < 4; ++t)
#pragma unroll
                for (int r = 0; r < 4; ++r)
                    comb[(((slot * 2 + s) * 64) + l) * 17 + t * 4 + r] = c4[s][t][r];
        if (l < 16) { zbs[slot][0][l] = z[0]; zbs[slot][1][l] = z[1]; }
    }
    __syncthreads();

    if (w == 0) {
#pragma unroll
        for (int slot = 0; slot < 7; ++slot) {
#pragma unroll
            for (int s = 0; s < 2; ++s)
#pragma unroll
                for (int t = 0; t < 4; ++t)
#pragma unroll
                    for (int r = 0; r < 4; ++r)
                        c4[s][t][r] += comb[(((slot * 2 + s) * 64) + l) * 17 + t * 4 + r];
            z[0] += zbs[slot][0][m];
            z[1] += zbs[slot][1][m];
        }

#pragma unroll
        for (int s = 0; s < 2; ++s) {
            // C layout: col = l&15, row = q*4 + reg
            float p[4] = {0.f, 0.f, 0.f, 0.f};
#pragma unroll
            for (int r = 0; r < 4; ++r)
#pragma unroll
                for (int t = 0; t < 4; ++t) p[r] = fmaf(c4[s][t][r], c4[s][t][r], p[r]);
#pragma unroll
            for (int mask = 1; mask < 16; mask <<= 1)
#pragma unroll
                for (int r = 0; r < 4; ++r) p[r] += __shfl_xor(p[r], mask);

            float zrow = __shfl(z[s], q * 4 + m, 16);
            if (m < 4) out[row0 + s * 16 + q * 4 + m] = 0.5f * (p[m] - zrow);
        }
    }
}

extern "C" void kernel_launch(void* const* d_in, const int* in_sizes, int n_in,
                              void* d_out, int out_size, void* d_ws, size_t ws_size,
                              hipStream_t stream) {
    const float* x = (const float*)d_in[0];      // (16384, 1024) fp32
    const float* v = (const float*)d_in[1];      // (1024, 64) fp32
    float* out = (float*)d_out;                  // (16384, 1) fp32

    unsigned short* bh = (unsigned short*)d_ws;                    // 131072 B
    float* wc = (float*)((char*)d_ws + 131072);                    //   4096 B

    const int B = in_sizes[0] / XD;              // 16384

    hipLaunchKernelGGL(prep_kernel, dim3(36), dim3(256), 0, stream, v, bh, wc);
    hipLaunchKernelGGL(cross_r14, dim3(B / 32), dim3(512), 0, stream,
                       x, bh, wc, out);
}

// Round 15
// 97.909 us; speedup vs baseline: 1.1206x; 1.0441x over previous
//
#include <hip/hip_runtime.h>

// Problem: B=16384, X_DIM=1024, K=64, fp32 in/out.
// out[b] = 0.5 * ( sum_k (x_b . V[:,k])^2  -  sum_i x_bi^2 w_i ),  w_i = sum_k V[i][k]^2
//
// R15 = R12 (best, 98.8) with staging replaced by async global->LDS DMA:
//  - 8x global_load_lds_dwordx4 per wave (1 KB contiguous each side, no VGPR
//    round trip, ~32 VGPRs freed) -- the guide's biggest measured lever (m97).
//  - DMA forbids swizzle -> bank spread comes from row PITCH=1036 floats:
//    A-frag b128 start bank = 4*((3m+2q)%8), uniform -> 8 words/bank (floor).
//    Rows 16B-aligned (4144 B); each 1 KB DMA segment stays within its row.
//  - K-loop, repack (RNE+v_perm), z-path, combine: identical to R12.

typedef short short8 __attribute__((ext_vector_type(8)));   // 8 bf16 = 4 VGPRs
typedef float f32x4 __attribute__((ext_vector_type(4)));

constexpr int XD = 1024;
constexpr int KD = 64;
constexpr int PITCH = 1036;   // floats; 12 mod 32 -> uniform A-frag bank spread

static __device__ __forceinline__ unsigned short f2bf(float f) {
    union { float f; unsigned u; } v; v.f = f;
    unsigned r = v.u + 0x7FFFu + ((v.u >> 16) & 1u);   // RNE
    return (unsigned short)(r >> 16);
}
static __device__ __forceinline__ unsigned fbits(float f) {
    union { float f; unsigned u; } v; v.f = f; return v.u;
}
static __device__ __forceinline__ void load_lds16(const float* g, float* l) {
    __builtin_amdgcn_global_load_lds(
        (const __attribute__((address_space(1))) unsigned int*)g,
        (__attribute__((address_space(3))) unsigned int*)l,
        16, 0, 0);   // 16 B/lane: emits global_load_lds_dwordx4
}

// ---- prep: blocks 0..31 build bf16 B-fragments (RNE); 32..35 build w ----
// B-fragment layout (mfma_f32_16x16x32_bf16): lane l holds B[k=(l>>4)*8+j][n=l&15]
// ws: bh @ 0 (131072 B) | wc @ 131072 (4096 B)
__global__ void prep_kernel(const float* __restrict__ v,
                            unsigned short* __restrict__ bh,
                            float* __restrict__ wc) {
    if (blockIdx.x < 32) {
        int idx = blockIdx.x * 256 + threadIdx.x;
        int it = idx >> 8;
        int r  = idx & 255;
        int t  = r >> 6;
        int l  = r & 63;
        int q  = l >> 4, m = l & 15;
        int base_i = it * 32 + q * 8;
        int n = t * 16 + m;
        size_t fo = ((size_t)(it * 4 + t) * 64 + l) * 8;
#pragma unroll
        for (int j = 0; j < 8; ++j) {
            float val = v[(size_t)(base_i + j) * KD + n];
            bh[fo + j] = f2bf(val);
        }
    } else {
        int i = (blockIdx.x - 32) * 256 + threadIdx.x;   // 0..1023
        const f32x4* vp = (const f32x4*)(v + (size_t)i * KD);
        f32x4 tv[16];
#pragma unroll
        for (int qq = 0; qq < 16; ++qq) tv[qq] = vp[qq];
        float s = 0.f;
#pragma unroll
        for (int qq = 0; qq < 16; ++qq) {
            s = fmaf(tv[qq].x, tv[qq].x, s); s = fmaf(tv[qq].y, tv[qq].y, s);
            s = fmaf(tv[qq].z, tv[qq].z, s); s = fmaf(tv[qq].w, tv[qq].w, s);
        }
        wc[i] = s;
    }
}

// ---- main: 512 thr / 8 waves; block = 16 full rows; wave = 4 i-tiles ----
__global__ __launch_bounds__(512, 4)
void cross_r15(const float* __restrict__ x,
               const unsigned short* __restrict__ bh,
               const float* __restrict__ wc,
               float* __restrict__ out) {
    // xbuf: 16 rows x PITCH floats = 66,304 B (DMA-staged, pitch-banked).
    // After the post-loop barrier the front is reused as the combine area.
    __shared__ __align__(16) float xbuf[16 * PITCH];
    __shared__ float wlds[XD];         // 4096 B
    __shared__ float zb[7][16];        //  448 B   (total ~71 KB -> 2 blocks/CU)

    const int tid = threadIdx.x;
    const int l = tid & 63;
    const int w = __builtin_amdgcn_readfirstlane(tid >> 6);   // wave 0..7
    const int q = l >> 4, m = l & 15;
    const int row0 = blockIdx.x * 16;

    // stage w (512 thr x float2, coalesced aligned)
    *(float2*)&wlds[tid * 2] = *(const float2*)(wc + tid * 2);

    // ---- stage x: 8 async DMAs/wave; (row r, seg s): 1 KB contiguous both sides ----
#pragma unroll
    for (int j = 0; j < 8; ++j) {
        const int idx = w * 8 + j;            // 0..63
        const int r = idx >> 2, s = idx & 3;
        const float* g = x + (size_t)(row0 + r) * XD + s * 256 + l * 4;
        float* dst = &xbuf[r * PITCH + s * 256];   // wave-uniform base; HW adds lane*16
        load_lds16(g, dst);
    }
    __syncthreads();   // compiler drains vmcnt before barrier -> DMAs complete

    // ---- compute: wave w -> i-tiles 4w .. 4w+3 ----
    f32x4 c4[4];
#pragma unroll
    for (int t = 0; t < 4; ++t) c4[t] = f32x4{0.f, 0.f, 0.f, 0.f};
    float z = 0.f;

    const short8* bhp = (const short8*)bh;

#pragma unroll
    for (int ii = 0; ii < 4; ++ii) {
        const int it = w * 4 + ii;
        const size_t fbase = (size_t)(it * 4) * 64 + l;

        // A source: row m, floats it*32 + q*8 .. +7 (pitch-banked, 8 words/bank)
        const int base = m * PITCH + it * 32 + q * 8;
        f32x4 xa = *(const f32x4*)&xbuf[base];
        f32x4 xb = *(const f32x4*)&xbuf[base + 4];

        const float* wp = &wlds[it * 32 + q * 8];
        f32x4 wa = *(const f32x4*)wp, wb = *(const f32x4*)(wp + 4);
        float xs[8] = {xa.x, xa.y, xa.z, xa.w, xb.x, xb.y, xb.z, xb.w};
        z = fmaf(xs[0]*xs[0], wa.x, z); z = fmaf(xs[1]*xs[1], wa.y, z);
        z = fmaf(xs[2]*xs[2], wa.z, z); z = fmaf(xs[3]*xs[3], wa.w, z);
        z = fmaf(xs[4]*xs[4], wb.x, z); z = fmaf(xs[5]*xs[5], wb.y, z);
        z = fmaf(xs[6]*xs[6], wb.z, z); z = fmaf(xs[7]*xs[7], wb.w, z);

        // RNE bf16 pack of x (pairwise via v_perm)
        unsigned ahp[4];
#pragma unroll
        for (int jp = 0; jp < 4; ++jp) {
            unsigned u0 = fbits(xs[2 * jp]);
            unsigned u1 = fbits(xs[2 * jp + 1]);
            u0 += 0x7FFFu + ((u0 >> 16) & 1u);
            u1 += 0x7FFFu + ((u1 >> 16) & 1u);
            ahp[jp] = __builtin_amdgcn_perm(u1, u0, 0x07060302u);  // {hi16(u1),hi16(u0)}
        }
        short8 ah;
#pragma unroll
        for (int jp = 0; jp < 4; ++jp) {
            ah[2*jp]   = (short)(ahp[jp] & 0xFFFF);
            ah[2*jp+1] = (short)(ahp[jp] >> 16);
        }

        // 4 independent MFMA chains (one per col-tile t)
#pragma unroll
        for (int t = 0; t < 4; ++t) {
            short8 vh = bhp[fbase + (size_t)t * 64];
            c4[t] = __builtin_amdgcn_mfma_f32_16x16x32_bf16(ah, vh, c4[t], 0, 0, 0);
        }
    }

    // z: sum over q-chunks -> full-q partial z for row m (this wave's i-range)
    z += __shfl_xor(z, 16);
    z += __shfl_xor(z, 32);

    __syncthreads();   // all xbuf reads done; reuse as combine area
    float* comb = xbuf;   // 7 slots x 64 lanes x 17 floats = 7616 <= 16576

    if (w > 0) {
        const int s = w - 1;
#pragma unroll
        for (int t = 0; t < 4; ++t)
#pragma unroll
            for (int r = 0; r < 4; ++r) comb[(s * 64 + l) * 17 + t * 4 + r] = c4[t][r];
        if (l < 16) zb[s][l] = z;
    }
    __syncthreads();

    if (w == 0) {
#pragma unroll
        for (int s = 0; s < 7; ++s) {
#pragma unroll
            for (int t = 0; t < 4; ++t)
#pragma unroll
                for (int r = 0; r < 4; ++r) c4[t][r] += comb[(s * 64 + l) * 17 + t * 4 + r];
            z += zb[s][m];
        }

        // C layout: col = l&15, row = q*4 + reg
        float p[4] = {0.f, 0.f, 0.f, 0.f};
#pragma unroll
        for (int r = 0; r < 4; ++r)
#pragma unroll
            for (int t = 0; t < 4; ++t) p[r] = fmaf(c4[t][r], c4[t][r], p[r]);
#pragma unroll
        for (int mask = 1; mask < 16; mask <<= 1)
#pragma unroll
            for (int r = 0; r < 4; ++r) p[r] += __shfl_xor(p[r], mask);

        float zrow = __shfl(z, q * 4 + m, 16);
        if (m < 4) out[row0 + q * 4 + m] = 0.5f * (p[m] - zrow);
    }
}

extern "C" void kernel_launch(void* const* d_in, const int* in_sizes, int n_in,
                              void* d_out, int out_size, void* d_ws, size_t ws_size,
                              hipStream_t stream) {
    const float* x = (const float*)d_in[0];      // (16384, 1024) fp32
    const float* v = (const float*)d_in[1];      // (1024, 64) fp32
    float* out = (float*)d_out;                  // (16384, 1) fp32

    unsigned short* bh = (unsigned short*)d_ws;                    // 131072 B
    float* wc = (float*)((char*)d_ws + 131072);                    //   4096 B

    const int B = in_sizes[0] / XD;              // 16384

    hipLaunchKernelGGL(prep_kernel, dim3(36), dim3(256), 0, stream, v, bh, wc);
    hipLaunchKernelGGL(cross_r15, dim3(B / 16), dim3(512), 0, stream,
                       x, bh, wc, out);
}